// Round 2
// baseline (61.285 us; speedup 1.0000x reference)
//
#include <hip/hip_runtime.h>

#define N_TASKS 16
#define LMAX 64
#define LDS_STRIDE 68  // 68%32=4 -> tasks staggered across banks; keeps 16B alignment

typedef float f32x4 __attribute__((ext_vector_type(4)));

__global__ __launch_bounds__(256) void MultiElementWiseAffine_kernel(
    const float* __restrict__ input,      // [B]
    const int*   __restrict__ task_ids,   // [B]
    const float* __restrict__ offsets,    // [N_TASKS*LMAX]
    const float* __restrict__ disc,       // [N_TASKS*LMAX]
    const int*   __restrict__ lengths,    // [N_TASKS]
    f32x4*       __restrict__ out,        // [B*16] float4 view of [B][64]
    int total4)                           // B*16
{
    __shared__ alignas(16) float s_off[N_TASKS * LDS_STRIDE];
    __shared__ alignas(16) float s_mdisc[N_TASKS * LDS_STRIDE];

    // Stage tables; fold the validity mask into the discrimination table.
    for (int i = threadIdx.x; i < N_TASKS * LMAX; i += blockDim.x) {
        int t = i >> 6;          // task
        int k = i & (LMAX - 1);  // threshold index
        s_off[t * LDS_STRIDE + k]   = offsets[i];
        s_mdisc[t * LDS_STRIDE + k] = (k < lengths[t]) ? disc[i] : 0.0f;
    }
    __syncthreads();

    const int stride = gridDim.x * blockDim.x;
    int g = blockIdx.x * blockDim.x + threadIdx.x;

#define BODY(G)                                                         \
    {                                                                   \
        int row = (G) >> 4;                                             \
        int k4  = (G) & 15;                                             \
        int t   = task_ids[row];                                        \
        float x = input[row];                                           \
        const float* o = &s_off[t * LDS_STRIDE + (k4 << 2)];            \
        const float* m = &s_mdisc[t * LDS_STRIDE + (k4 << 2)];          \
        f32x4 r;                                                        \
        r.x = m[0] * (x + o[0]);                                        \
        r.y = m[1] * (x + o[1]);                                        \
        r.z = m[2] * (x + o[2]);                                        \
        r.w = m[3] * (x + o[3]);                                        \
        __builtin_nontemporal_store(r, &out[G]);                        \
    }

    // 4x-unrolled main loop: 4 independent gather->LDS->store chains in flight.
    for (; g < total4 - 3 * stride; g += 4 * stride) {
        BODY(g);
        BODY(g + stride);
        BODY(g + 2 * stride);
        BODY(g + 3 * stride);
    }
    for (; g < total4; g += stride) BODY(g);
#undef BODY
}

extern "C" void kernel_launch(void* const* d_in, const int* in_sizes, int n_in,
                              void* d_out, int out_size, void* d_ws, size_t ws_size,
                              hipStream_t stream) {
    const float* input    = (const float*)d_in[0];
    const int*   task_ids = (const int*)d_in[1];
    const float* offsets  = (const float*)d_in[2];
    const float* disc     = (const float*)d_in[3];
    const int*   lengths  = (const int*)d_in[4];
    f32x4*       out      = (f32x4*)d_out;

    int total4 = out_size / 4;           // B * 16
    int block  = 256;
    int grid   = 2048;                   // 524288 threads, 32 float4s each

    MultiElementWiseAffine_kernel<<<grid, block, 0, stream>>>(
        input, task_ids, offsets, disc, lengths, out, total4);
}